// Round 4
// baseline (104.351 us; speedup 1.0000x reference)
//
#include <hip/hip_runtime.h>
#include <hip/hip_bf16.h>

#define SREF 2048
#define DHEAD 128
#define KVBLK 64
#define NTHREADS 256
#define NTILES (SREF / KVBLK)
#define PSTR 72
#define QSCALE 0.12751743f   /* log2(e)/sqrt(128) */
#define THRLOG 8.0f          /* defer-max threshold, log2 domain */

typedef short bf16x8 __attribute__((ext_vector_type(8)));
typedef float f32x4 __attribute__((ext_vector_type(4)));
typedef float f32x16 __attribute__((ext_vector_type(16)));

typedef const __attribute__((address_space(1))) void* gas_t;
typedef __attribute__((address_space(3))) void* las_t;

__device__ __forceinline__ ushort f2bf(float x) {
    unsigned u = __builtin_bit_cast(unsigned, x);
    u += 0x7fffu + ((u >> 16) & 1u);
    return (ushort)(u >> 16);
}

__device__ __forceinline__ float fexp2(float x) {
#if __has_builtin(__builtin_amdgcn_exp2f)
    return __builtin_amdgcn_exp2f(x);
#else
    return exp2f(x);
#endif
}

__device__ __forceinline__ unsigned cvtpk(float lo, float hi) {
    unsigned r;
    asm("v_cvt_pk_bf16_f32 %0, %1, %2" : "=v"(r) : "v"(lo), "v"(hi));
    return r;
}

// ---------------- precompute: K -> bf16, V -> V^T bf16 ----------------
__global__ __launch_bounds__(NTHREADS) void preconv_kernel(
    const float* __restrict__ K, const float* __restrict__ V,
    ushort* __restrict__ Kb, ushort* __restrict__ VTb)
{
    __shared__ ushort T[DHEAD * PSTR];
    const int t  = threadIdx.x;
    const int bh = blockIdx.y;
    const int s0 = blockIdx.x * KVBLK;
    const size_t base = (size_t)bh * SREF * DHEAD;

    const float* kb = K + base + (size_t)s0 * DHEAD;
    ushort* kout = Kb + base + (size_t)s0 * DHEAD;
    #pragma unroll
    for (int i = 0; i < 8; ++i) {
        int idx = t + i * NTHREADS;
        float4 f = *(const float4*)(kb + idx * 4);
        ushort4 h; h.x = f2bf(f.x); h.y = f2bf(f.y); h.z = f2bf(f.z); h.w = f2bf(f.w);
        *(ushort4*)(kout + idx * 4) = h;
    }

    const float* vb = V + base + (size_t)s0 * DHEAD;
    #pragma unroll
    for (int i = 0; i < 8; ++i) {
        const int key = (t & 31) + 32 * (i & 1);
        const int d4  = (t >> 5) + 8 * (i >> 1);
        float4 f = *(const float4*)(vb + key * DHEAD + d4 * 4);
        T[(d4 * 4 + 0) * PSTR + key] = f2bf(f.x);
        T[(d4 * 4 + 1) * PSTR + key] = f2bf(f.y);
        T[(d4 * 4 + 2) * PSTR + key] = f2bf(f.z);
        T[(d4 * 4 + 3) * PSTR + key] = f2bf(f.w);
    }
    __syncthreads();

    ushort* vt = VTb + (size_t)bh * DHEAD * SREF + s0;
    #pragma unroll
    for (int i = 0; i < 4; ++i) {
        int idx = t + i * NTHREADS;
        int d = idx >> 3;
        int c = (idx & 7) * 8;
        bf16x8 v = *(const bf16x8*)&T[d * PSTR + c];
        *(bf16x8*)(vt + (size_t)d * SREF + c) = v;
    }
}

// softmax on one tile's scores (s0,s1) -> pa frags; updates mrun/lsumh/acc
__device__ __forceinline__ void softmax_step(
    f32x16& s0, f32x16& s1, float& mrun, float& lsumh,
    f32x16* acc, bf16x8* pa)
{
    // depth-5 tree max over 32 values (was 31-deep serial chain)
    float m0[8];
    #pragma unroll
    for (int i = 0; i < 8; ++i)
        m0[i] = fmaxf(fmaxf(s0[i], s0[i + 8]), fmaxf(s1[i], s1[i + 8]));
    float pmax = fmaxf(fmaxf(fmaxf(m0[0], m0[1]), fmaxf(m0[2], m0[3])),
                       fmaxf(fmaxf(m0[4], m0[5]), fmaxf(m0[6], m0[7])));
    pmax = fmaxf(pmax, __shfl_xor(pmax, 32));

    if (!__all(pmax <= mrun + THRLOG)) {        // defer-max (T13)
        const float mnew  = fmaxf(mrun, pmax);
        const float alpha = fexp2(mrun - mnew);
        mrun = mnew;
        lsumh *= alpha;
        #pragma unroll
        for (int db = 0; db < 4; ++db)
            #pragma unroll
            for (int i = 0; i < 16; ++i) acc[db][i] *= alpha;
    }

    float r0 = 0.f, r1 = 0.f, r2 = 0.f, r3 = 0.f;   // 4-way partial sums (ILP)
    #pragma unroll
    for (int i = 0; i < 16; i += 4) {
        s0[i]   = fexp2(s0[i]   - mrun); r0 += s0[i];
        s0[i+1] = fexp2(s0[i+1] - mrun); r1 += s0[i+1];
        s0[i+2] = fexp2(s0[i+2] - mrun); r2 += s0[i+2];
        s0[i+3] = fexp2(s0[i+3] - mrun); r3 += s0[i+3];
    }
    #pragma unroll
    for (int i = 0; i < 16; i += 4) {
        s1[i]   = fexp2(s1[i]   - mrun); r0 += s1[i];
        s1[i+1] = fexp2(s1[i+1] - mrun); r1 += s1[i+1];
        s1[i+2] = fexp2(s1[i+2] - mrun); r2 += s1[i+2];
        s1[i+3] = fexp2(s1[i+3] - mrun); r3 += s1[i+3];
    }
    lsumh += (r0 + r1) + (r2 + r3);

    // P -> A-side bf16 frags in-register (T12: cvt_pk + permlane32_swap)
    #pragma unroll
    for (int kb = 0; kb < 2; ++kb) {
        #pragma unroll
        for (int c = 0; c < 2; ++c) {
            unsigned x0, x1, y0, y1;
            if (kb == 0) {
                x0 = cvtpk(s0[8*c+0], s0[8*c+1]); x1 = cvtpk(s0[8*c+2], s0[8*c+3]);
                y0 = cvtpk(s0[8*c+4], s0[8*c+5]); y1 = cvtpk(s0[8*c+6], s0[8*c+7]);
            } else {
                x0 = cvtpk(s1[8*c+0], s1[8*c+1]); x1 = cvtpk(s1[8*c+2], s1[8*c+3]);
                y0 = cvtpk(s1[8*c+4], s1[8*c+5]); y1 = cvtpk(s1[8*c+6], s1[8*c+7]);
            }
            asm volatile("v_permlane32_swap_b32 %0, %1" : "+v"(x0), "+v"(y0));
            asm volatile("v_permlane32_swap_b32 %0, %1" : "+v"(x1), "+v"(y1));
            union { unsigned u[4]; bf16x8 v; } U;
            U.u[0] = x0; U.u[1] = x1; U.u[2] = y0; U.u[3] = y1;
            pa[kb * 2 + c] = U.v;
        }
    }
}

// ---------------- main attention kernel: 4 waves x 32 q-rows, 32x32 MFMA ----------------
// LDS: Kbuf[b] at b*16384 (16KB); Vbuf[b] at 32768+b*16384 (16KB); epilogue overlays.
// Pipeline (1 barrier/phase): phase t = {vmcnt(0); bar; issue STAGE K(t+2),V(t+1);
//   softmax(t) || QK^T(t+1); PV(t)}.  Safety: stages issued after the barrier touch only
//   buffers whose last readers (QK(t) in phase t-1, PV(t-1) in phase t-1) finished before
//   it; each wave drains its own gload_lds (vmcnt(0)) before the barrier preceding the
//   first cross-wave read of that data.
__global__ __launch_bounds__(NTHREADS, 2) void attn_fwd_kernel(
    const float* __restrict__ Q, const ushort* __restrict__ Kb,
    const ushort* __restrict__ VTb, float* __restrict__ O)
{
    __shared__ __align__(16) char smem[67584];

    const int t    = threadIdx.x;
    const int lane = t & 63;
    const int wv   = t >> 6;
    const int hi   = lane >> 5;
    const int q5   = lane & 31;
    const int swz  = (lane & 7) << 4;

    const int bh = blockIdx.y;
    const int q0 = blockIdx.x * 128;
    const size_t base = (size_t)bh * SREF * DHEAD;

    bf16x8 qf[8];
    {
        const float* qrow = Q + base + (size_t)(q0 + wv * 32 + q5) * DHEAD;
        #pragma unroll
        for (int dk = 0; dk < 8; ++dk) {
            const int d0 = dk * 16 + hi * 8;
            float4 a = *(const float4*)(qrow + d0);
            float4 b = *(const float4*)(qrow + d0 + 4);
            bf16x8 f;
            f[0] = (short)f2bf(a.x * QSCALE); f[1] = (short)f2bf(a.y * QSCALE);
            f[2] = (short)f2bf(a.z * QSCALE); f[3] = (short)f2bf(a.w * QSCALE);
            f[4] = (short)f2bf(b.x * QSCALE); f[5] = (short)f2bf(b.y * QSCALE);
            f[6] = (short)f2bf(b.z * QSCALE); f[7] = (short)f2bf(b.w * QSCALE);
            qf[dk] = f;
        }
    }

    const char* ksrcb = (const char*)(Kb + base);
    const char* vsrcb = (const char*)(VTb + (size_t)bh * DHEAD * SREF);

    const int kbaseL = q5 * 256 + ((hi * 16) ^ swz);
    const int vbaseL = q5 * 128 + ((hi * 16) ^ swz);

#define KOFF(b) ((b) * 16384)
#define VOFF(b) (32768 + (b) * 16384)

#define STAGE_K(b, kv0) do {                                                    \
    const char* kt_ = ksrcb + (size_t)(kv0) * (DHEAD * 2);                      \
    _Pragma("unroll")                                                           \
    for (int i_ = 0; i_ < 4; ++i_) {                                            \
        int L_ = t * 16 + i_ * 4096;                                            \
        int r_ = L_ >> 8;                                                       \
        __builtin_amdgcn_global_load_lds(                                       \
            (gas_t)(const void*)(kt_ + (L_ ^ ((r_ & 7) << 4))),                 \
            (las_t)(void*)(smem + KOFF(b) + L_), 16, 0, 0);                     \
    }                                                                           \
} while (0)

#define STAGE_V(b, kv0) do {                                                    \
    const char* vt_ = vsrcb + (size_t)(kv0) * 2;                                \
    _Pragma("unroll")                                                           \
    for (int i_ = 0; i_ < 4; ++i_) {                                            \
        int L_ = t * 16 + i_ * 4096;                                            \
        int d_ = L_ >> 7;                                                       \
        int c_ = L_ & 127;                                                      \
        __builtin_amdgcn_global_load_lds(                                       \
            (gas_t)(const void*)(vt_ + (size_t)d_ * (SREF * 2) + (c_ ^ ((d_ & 7) << 4))), \
            (las_t)(void*)(smem + VOFF(b) + L_), 16, 0, 0);                     \
    }                                                                           \
} while (0)

#define QK_REGION(sd0, sd1, kO_) do {                                           \
    _Pragma("unroll")                                                           \
    for (int i_ = 0; i_ < 16; ++i_) { sd0[i_] = 0.f; sd1[i_] = 0.f; }           \
    _Pragma("unroll")                                                           \
    for (int dk_ = 0; dk_ < 8; ++dk_) {                                         \
        bf16x8 kf0 = *(const bf16x8*)(smem + (kO_) + (kbaseL ^ (dk_ << 5)));    \
        sd0 = __builtin_amdgcn_mfma_f32_32x32x16_bf16(kf0, qf[dk_], sd0, 0, 0, 0); \
        bf16x8 kf1 = *(const bf16x8*)(smem + (kO_) + 8192 + (kbaseL ^ (dk_ << 5))); \
        sd1 = __builtin_amdgcn_mfma_f32_32x32x16_bf16(kf1, qf[dk_], sd1, 0, 0, 0); \
    }                                                                           \
} while (0)

#define PV_REGION(pa_, vO_) do {                                                \
    __builtin_amdgcn_s_setprio(1);                                              \
    _Pragma("unroll")                                                           \
    for (int db_ = 0; db_ < 4; ++db_) {                                         \
        _Pragma("unroll")                                                       \
        for (int ks_ = 0; ks_ < 4; ++ks_) {                                     \
            bf16x8 vf = *(const bf16x8*)(smem + (vO_) + db_ * 4096 + (vbaseL ^ (ks_ << 5))); \
            acc[db_] = __builtin_amdgcn_mfma_f32_32x32x16_bf16(vf, pa_[ks_], acc[db_], 0, 0, 0); \
        }                                                                       \
    }                                                                           \
    __builtin_amdgcn_s_setprio(0);                                              \
} while (0)

#define PHASE_SYNC() do {                                                       \
    asm volatile("s_waitcnt vmcnt(0)" ::: "memory");                            \
    __builtin_amdgcn_s_barrier();                                               \
    __builtin_amdgcn_sched_barrier(0);                                          \
} while (0)

    float mrun = -1e30f, lsumh = 0.0f;
    f32x16 acc[4];
    #pragma unroll
    for (int db = 0; db < 4; ++db)
        #pragma unroll
        for (int i = 0; i < 16; ++i) acc[db][i] = 0.0f;

    f32x16 sA0, sA1, sB0, sB1;
    bf16x8 pa[4];

    // ---- prologue: stage K(0),K(1),V(0); compute scores(0) ----
    STAGE_K(0, 0);
    STAGE_K(1, KVBLK);
    STAGE_V(0, 0);
    asm volatile("s_waitcnt vmcnt(16)" ::: "memory");   // K(0) retired (own share)
    __builtin_amdgcn_s_barrier();
    __builtin_amdgcn_sched_barrier(0);
    QK_REGION(sA0, sA1, KOFF(0));                       // scores(0)

    for (int u = 0; u < 15; ++u) {
        const int t0 = 2 * u;
        // ---- even phase t0: sm(sA) || QK(t0+1); PV(t0) ----
        PHASE_SYNC();
        STAGE_K(0, (t0 + 2) * KVBLK);
        STAGE_V(1, (t0 + 1) * KVBLK);
        softmax_step(sA0, sA1, mrun, lsumh, acc, pa);
        QK_REGION(sB0, sB1, KOFF(1));                   // scores(t0+1)
        PV_REGION(pa, VOFF(0));                         // PV(t0)
        // ---- odd phase t0+1: sm(sB) || QK(t0+2); PV(t0+1) ----
        PHASE_SYNC();
        STAGE_K(1, (t0 + 3) * KVBLK);
        STAGE_V(0, (t0 + 2) * KVBLK);
        softmax_step(sB0, sB1, mrun, lsumh, acc, pa);
        QK_REGION(sA0, sA1, KOFF(0));                   // scores(t0+2)
        PV_REGION(pa, VOFF(1));                         // PV(t0+1)
    }
    // ---- tail t=30 ----
    PHASE_SYNC();
    STAGE_V(1, 31 * KVBLK);
    softmax_step(sA0, sA1, mrun, lsumh, acc, pa);
    QK_REGION(sB0, sB1, KOFF(1));                       // scores(31)
    PV_REGION(pa, VOFF(0));                             // PV(30)
    // ---- tail t=31 ----
    PHASE_SYNC();
    softmax_step(sB0, sB1, mrun, lsumh, acc, pa);
    PV_REGION(pa, VOFF(1));                             // PV(31)

    // ---- epilogue: O^T -> O via per-wave LDS transpose ----
    __syncthreads();

    const float lsum = lsumh + __shfl_xor(lsumh, 32);
    const float inv  = 1.0f / lsum;
    const int eb = wv * 16896;
    #pragma unroll
    for (int db = 0; db < 4; ++db) {
        #pragma unroll
        for (int c = 0; c < 4; ++c) {
            f32x4 v;
            v[0] = acc[db][4*c+0] * inv;
            v[1] = acc[db][4*c+1] * inv;
            v[2] = acc[db][4*c+2] * inv;
            v[3] = acc[db][4*c+3] * inv;
            *(f32x4*)(smem + eb + q5 * 528 + db * 128 + c * 32 + hi * 16) = v;
        }
    }
    #pragma unroll
    for (int i = 0; i < 16; ++i) {
        const int flat  = lane + i * 64;
        const int row   = flat >> 5;
        const int chunk = flat & 31;
        f32x4 v = *(const f32x4*)(smem + eb + row * 528 + chunk * 16);
        *(f32x4*)(O + base + (size_t)(q0 + wv * 32 + row) * DHEAD + chunk * 4) = v;
    }
#undef STAGE_K
#undef STAGE_V
#undef QK_REGION
#undef PV_REGION
#undef PHASE_SYNC
#undef KOFF
#undef VOFF
}

// ---------------- fallback (known-correct; used only if ws too small) ----------------
__global__ __launch_bounds__(NTHREADS) void attn_fwd_fallback(
    const float* __restrict__ Q, const float* __restrict__ K,
    const float* __restrict__ V, float* __restrict__ O)
{
    __shared__ ushort Ksh[KVBLK * 136];
    __shared__ ushort Vsh[DHEAD * 72];
    __shared__ ushort Psh[4][16 * PSTR];

    const int t    = threadIdx.x;
    const int lane = t & 63;
    const int wv   = t >> 6;
    const int lq   = lane & 15;
    const int kh   = lane >> 4;

    const int bh = blockIdx.y;
    const int q0 = blockIdx.x * 64;
    const size_t base = (size_t)bh * SREF * DHEAD;

    const float scale = 0.08838834764831845f;
    bf16x8 qf[4];
    {
        const float* qrow = Q + base + (size_t)(q0 + wv * 16 + lq) * DHEAD;
        #pragma unroll
        for (int kk = 0; kk < 4; ++kk) {
            const int d0 = kk * 32 + kh * 8;
            float4 a = *(const float4*)(qrow + d0);
            float4 b = *(const float4*)(qrow + d0 + 4);
            bf16x8 f;
            f[0] = (short)f2bf(a.x * scale); f[1] = (short)f2bf(a.y * scale);
            f[2] = (short)f2bf(a.z * scale); f[3] = (short)f2bf(a.w * scale);
            f[4] = (short)f2bf(b.x * scale); f[5] = (short)f2bf(b.y * scale);
            f[6] = (short)f2bf(b.z * scale); f[7] = (short)f2bf(b.w * scale);
            qf[kk] = f;
        }
    }

    float mrun[4], lrun[4];
    f32x4 acc_o[8];
    #pragma unroll
    for (int r = 0; r < 4; ++r) { mrun[r] = -1e30f; lrun[r] = 0.0f; }
    #pragma unroll
    for (int db = 0; db < 8; ++db) acc_o[db] = (f32x4){0.f, 0.f, 0.f, 0.f};

    for (int kv0 = 0; kv0 < SREF; kv0 += KVBLK) {
        __syncthreads();
        const float* kbase = K + base + (size_t)kv0 * DHEAD;
        #pragma unroll
        for (int i = 0; i < 8; ++i) {
            const int idx = t + i * NTHREADS;
            const int row = idx >> 5;
            const int c4  = idx & 31;
            float4 f = *(const float4*)(kbase + row * DHEAD + c4 * 4);
            ushort4 h;
            h.x = f2bf(f.x); h.y = f2bf(f.y); h.z = f2bf(f.z); h.w = f2bf(f.w);
            *(ushort4*)&Ksh[row * 136 + c4 * 4] = h;
        }
        const float* vbase = V + base + (size_t)kv0 * DHEAD;
        #pragma unroll
        for (int i = 0; i < 8; ++i) {
            const int key = (t & 31) + 32 * (i & 1);
            const int d4  = (t >> 5) + 8 * (i >> 1);
            float4 f = *(const float4*)(vbase + key * DHEAD + d4 * 4);
            Vsh[(d4 * 4 + 0) * 72 + key] = f2bf(f.x);
            Vsh[(d4 * 4 + 1) * 72 + key] = f2bf(f.y);
            Vsh[(d4 * 4 + 2) * 72 + key] = f2bf(f.z);
            Vsh[(d4 * 4 + 3) * 72 + key] = f2bf(f.w);
        }
        __syncthreads();

        f32x4 accs[4];
        #pragma unroll
        for (int nb = 0; nb < 4; ++nb) accs[nb] = (f32x4){0.f, 0.f, 0.f, 0.f};
        #pragma unroll
        for (int kk = 0; kk < 4; ++kk) {
            #pragma unroll
            for (int nb = 0; nb < 4; ++nb) {
                bf16x8 kf = *(const bf16x8*)&Ksh[(nb * 16 + lq) * 136 + kk * 32 + kh * 8];
                accs[nb] = __builtin_amdgcn_mfma_f32_16x16x32_bf16(qf[kk], kf, accs[nb], 0, 0, 0);
            }
        }

        float ps[4][4];
        #pragma unroll
        for (int r = 0; r < 4; ++r) {
            float v = fmaxf(fmaxf(accs[0][r], accs[1][r]), fmaxf(accs[2][r], accs[3][r]));
            #pragma unroll
            for (int mk = 1; mk < 16; mk <<= 1) v = fmaxf(v, __shfl_xor(v, mk));
            const float mnew  = fmaxf(mrun[r], v);
            const float alpha = __expf(mrun[r] - mnew);
            mrun[r] = mnew;
            float rs = 0.0f;
            #pragma unroll
            for (int nb = 0; nb < 4; ++nb) {
                const float p = __expf(accs[nb][r] - mnew);
                ps[nb][r] = p;
                rs += p;
            }
            #pragma unroll
            for (int mk = 1; mk < 16; mk <<= 1) rs += __shfl_xor(rs, mk);
            lrun[r] = lrun[r] * alpha + rs;
            #pragma unroll
            for (int db = 0; db < 8; ++db) acc_o[db][r] *= alpha;
        }

        #pragma unroll
        for (int nb = 0; nb < 4; ++nb)
            #pragma unroll
            for (int r = 0; r < 4; ++r)
                Psh[wv][(kh * 4 + r) * PSTR + nb * 16 + lq] = f2bf(ps[nb][r]);

        #pragma unroll
        for (int ks = 0; ks < 2; ++ks) {
            bf16x8 pa = *(const bf16x8*)&Psh[wv][lq * PSTR + ks * 32 + kh * 8];
            #pragma unroll
            for (int db = 0; db < 8; ++db) {
                bf16x8 vf = *(const bf16x8*)&Vsh[(db * 16 + lq) * 72 + ks * 32 + kh * 8];
                acc_o[db] = __builtin_amdgcn_mfma_f32_16x16x32_bf16(pa, vf, acc_o[db], 0, 0, 0);
            }
        }
    }

    #pragma unroll
    for (int r = 0; r < 4; ++r) {
        const float inv = 1.0f / lrun[r];
        float* orow = O + base + (size_t)(q0 + wv * 16 + kh * 4 + r) * DHEAD;
        #pragma unroll
        for (int db = 0; db < 8; ++db)
            orow[db * 16 + lq] = acc_o[db][r] * inv;
    }
}

extern "C" void kernel_launch(void* const* d_in, const int* in_sizes, int n_in,
                              void* d_out, int out_size, void* d_ws, size_t ws_size,
                              hipStream_t stream) {
    const float* Q = (const float*)d_in[0];
    const float* K = (const float*)d_in[1];
    const float* V = (const float*)d_in[2];
    float* O = (float*)d_out;
    const int BH = in_sizes[0] / (SREF * DHEAD);
    const size_t nel = (size_t)BH * SREF * DHEAD;

    if (ws_size >= 2 * nel * sizeof(ushort)) {
        ushort* Kb  = (ushort*)d_ws;
        ushort* VTb = Kb + nel;
        preconv_kernel<<<dim3(SREF / KVBLK, BH), NTHREADS, 0, stream>>>(K, V, Kb, VTb);
        attn_fwd_kernel<<<dim3(SREF / 128, BH), NTHREADS, 0, stream>>>(Q, Kb, VTb, O);
    } else {
        attn_fwd_fallback<<<dim3(SREF / 64, BH), NTHREADS, 0, stream>>>(Q, K, V, O);
    }
}